// Round 1
// baseline (507.277 us; speedup 1.0000x reference)
//
#include <hip/hip_runtime.h>
#include <math.h>

// KGVAE: 2-layer RelGraphConv (bdd) + reparameterize.
// N=50000 nodes, E=400000 edges, H=64, R=200 rels, B=8 bases.
// Layout: h1 = ws[0 .. N*64), h2 = ws[N*64 .. N*64 + N*128).

// h1[n,j] = b1[j] + sum_k emb[h_ids[n],k] * lw1[k,j]
__global__ void selfloop1(const float* __restrict__ emb, const int* __restrict__ h_ids,
                          const float* __restrict__ lw, const float* __restrict__ bias,
                          float* __restrict__ h1, int n_nodes) {
    int idx = blockIdx.x * blockDim.x + threadIdx.x;
    int n = idx >> 6, j = idx & 63;
    if (n >= n_nodes) return;
    const float* frow = emb + (long)h_ids[n] * 64;
    float acc = bias[j];
#pragma unroll
    for (int k = 0; k < 64; ++k)
        acc = fmaf(frow[k], lw[k * 64 + j], acc);
    h1[idx] = acc;
}

// per-edge: msg[j] = norm * sum_i x[b*8+i] * w1[rel][b*64+i*8+o],  b=j>>3, o=j&7
__global__ void edge1(const float* __restrict__ emb, const int* __restrict__ h_ids,
                      const int* __restrict__ src, const int* __restrict__ dst,
                      const int* __restrict__ rel, const float* __restrict__ norm,
                      const float* __restrict__ w1, float* __restrict__ h1, int n_edges) {
    int e = blockIdx.x * 4 + (threadIdx.x >> 6);
    if (e >= n_edges) return;
    int lane = threadIdx.x & 63;
    int s = src[e], d = dst[e], r = rel[e];
    float nm = norm[e];
    float x = emb[(long)h_ids[s] * 64 + lane];
    const float* w = w1 + (long)r * 512;
    int b = lane >> 3, o = lane & 7;
    int xbase = lane & 56;  // b*8
    float acc = 0.f;
#pragma unroll
    for (int i = 0; i < 8; ++i) {
        float xi = __shfl(x, xbase + i, 64);
        acc = fmaf(xi, w[b * 64 + i * 8 + o], acc);
    }
    atomicAdd(&h1[(long)d * 64 + lane], acc * nm);
}

// h2[n,j] = b2[j] + sum_k relu(h1[n,k]) * lw2[k,j]   (j in [0,128))
__global__ void selfloop2(const float* __restrict__ h1, const float* __restrict__ lw,
                          const float* __restrict__ bias, float* __restrict__ h2, int n_nodes) {
    int idx = blockIdx.x * blockDim.x + threadIdx.x;
    int n = idx >> 7, j = idx & 127;
    if (n >= n_nodes) return;
    const float* row = h1 + (long)n * 64;
    float acc = bias[j];
#pragma unroll
    for (int k = 0; k < 64; ++k)
        acc = fmaf(fmaxf(row[k], 0.f), lw[k * 128 + j], acc);
    h2[idx] = acc;
}

// per-edge layer 2: lane handles outputs j=lane and j=lane+64; b=j>>4, o=j&15
__global__ void edge2(const float* __restrict__ h1,
                      const int* __restrict__ src, const int* __restrict__ dst,
                      const int* __restrict__ rel, const float* __restrict__ norm,
                      const float* __restrict__ w2, float* __restrict__ h2, int n_edges) {
    int e = blockIdx.x * 4 + (threadIdx.x >> 6);
    if (e >= n_edges) return;
    int lane = threadIdx.x & 63;
    int s = src[e], d = dst[e], r = rel[e];
    float nm = norm[e];
    float x = fmaxf(h1[(long)s * 64 + lane], 0.f);  // relu on gather
    const float* w = w2 + (long)r * 1024;
    int o = lane & 15;
    int bA = lane >> 4;      // output j = lane        (b in 0..3)
    int bB = bA + 4;         // output j = lane + 64   (b in 4..7)
    float accA = 0.f, accB = 0.f;
#pragma unroll
    for (int i = 0; i < 8; ++i) {
        float xa = __shfl(x, bA * 8 + i, 64);
        float xb = __shfl(x, bB * 8 + i, 64);
        accA = fmaf(xa, w[bA * 128 + i * 16 + o], accA);
        accB = fmaf(xb, w[bB * 128 + i * 16 + o], accB);
    }
    atomicAdd(&h2[(long)d * 128 + lane], accA * nm);
    atomicAdd(&h2[(long)d * 128 + 64 + lane], accB * nm);
}

// out = m + sqrt(softplus(raw_v)+1e-8) * eps
__global__ void epilogue(const float* __restrict__ h2, const float* __restrict__ eps,
                         float* __restrict__ out, int n_nodes) {
    int idx = blockIdx.x * blockDim.x + threadIdx.x;
    if (idx >= n_nodes * 64) return;
    int n = idx >> 6, j = idx & 63;
    float m = h2[(long)n * 128 + j];
    float rv = h2[(long)n * 128 + 64 + j];
    float sp = (rv > 20.f) ? rv : log1pf(expf(rv));
    float v = sp + 1e-8f;
    out[idx] = fmaf(sqrtf(v), eps[idx], m);
}

extern "C" void kernel_launch(void* const* d_in, const int* in_sizes, int n_in,
                              void* d_out, int out_size, void* d_ws, size_t ws_size,
                              hipStream_t stream) {
    const float* emb   = (const float*)d_in[0];
    const float* norm  = (const float*)d_in[1];
    const float* eps   = (const float*)d_in[2];
    const float* w1    = (const float*)d_in[3];
    const float* lw1   = (const float*)d_in[4];
    const float* b1    = (const float*)d_in[5];
    const float* w2    = (const float*)d_in[6];
    const float* lw2   = (const float*)d_in[7];
    const float* b2    = (const float*)d_in[8];
    const int*   h_ids = (const int*)d_in[9];
    const int*   src   = (const int*)d_in[10];
    const int*   dst   = (const int*)d_in[11];
    const int*   rel   = (const int*)d_in[12];
    float* out = (float*)d_out;

    int n_nodes = in_sizes[0] / 64;   // 50000
    int n_edges = in_sizes[10];       // 400000

    float* h1 = (float*)d_ws;                       // N*64 floats
    float* h2 = h1 + (size_t)n_nodes * 64;          // N*128 floats

    int blk = 256;
    // layer 1
    selfloop1<<<(n_nodes * 64 + blk - 1) / blk, blk, 0, stream>>>(emb, h_ids, lw1, b1, h1, n_nodes);
    edge1<<<(n_edges + 3) / 4, blk, 0, stream>>>(emb, h_ids, src, dst, rel, norm, w1, h1, n_edges);
    // layer 2
    selfloop2<<<(n_nodes * 128 + blk - 1) / blk, blk, 0, stream>>>(h1, lw2, b2, h2, n_nodes);
    edge2<<<(n_edges + 3) / 4, blk, 0, stream>>>(h1, src, dst, rel, norm, w2, h2, n_edges);
    // reparameterize
    epilogue<<<(n_nodes * 64 + blk - 1) / blk, blk, 0, stream>>>(h2, eps, out, n_nodes);
}

// Round 2
// 464.081 us; speedup vs baseline: 1.0931x; 1.0931x over previous
//
#include <hip/hip_runtime.h>
#include <math.h>

// KGVAE: 2-layer RelGraphConv (bdd) + reparameterize, gather formulation.
// N=50000, E=400000, H=64, R=200, B=8.
// R2: dst-CSR + gather (no fp atomics), layer2 fused with epilogue.
// ws layout: h1[N*64] f32 | deg[N] i32 | off[N+1] i32 | fill[N] i32 | eidx[E] i32

__global__ void zero_deg(int* __restrict__ deg, int n) {
    int i = blockIdx.x * blockDim.x + threadIdx.x;
    if (i < n) deg[i] = 0;
}

__global__ void hist(const int* __restrict__ dst, int* __restrict__ deg, int e) {
    int i = blockIdx.x * blockDim.x + threadIdx.x;
    if (i < e) atomicAdd(&deg[dst[i]], 1);
}

// single-block exclusive scan of deg -> off (off[n]=total); also zeroes fill.
__global__ void scan_deg(const int* __restrict__ deg, int* __restrict__ off,
                         int* __restrict__ fill, int n) {
    __shared__ int part[1024];
    int t = threadIdx.x;
    int chunk = (n + 1023) / 1024;
    int lo = t * chunk, hi = lo + chunk;
    if (hi > n) hi = n;
    int s = 0;
    for (int i = lo; i < hi; ++i) s += deg[i];
    part[t] = s;
    __syncthreads();
    for (int d = 1; d < 1024; d <<= 1) {
        int v = (t >= d) ? part[t - d] : 0;
        __syncthreads();
        part[t] += v;
        __syncthreads();
    }
    int run = part[t] - s;  // exclusive base for this chunk
    for (int i = lo; i < hi; ++i) { off[i] = run; run += deg[i]; }
    if (t == 1023) off[n] = part[1023];
    for (int i = t; i < n; i += 1024) fill[i] = 0;
}

__global__ void scatter(const int* __restrict__ dst, const int* __restrict__ off,
                        int* __restrict__ fill, int* __restrict__ eidx, int e) {
    int i = blockIdx.x * blockDim.x + threadIdx.x;
    if (i < e) {
        int d = dst[i];
        int p = off[d] + atomicAdd(&fill[d], 1);
        eidx[p] = i;
    }
}

// one wave per node: h1[n,:] = b1 + feat[n]@lw1 + sum_{e:dst=n} nm*bdd(feat[src],w1[rel])
__global__ void layer1(const float* __restrict__ emb, const int* __restrict__ h_ids,
                       const int* __restrict__ src, const int* __restrict__ rel,
                       const float* __restrict__ norm, const float* __restrict__ w1,
                       const float* __restrict__ lw1, const float* __restrict__ b1,
                       const int* __restrict__ off, const int* __restrict__ eidx,
                       float* __restrict__ h1, int n_nodes) {
    int n = blockIdx.x * (blockDim.x >> 6) + (threadIdx.x >> 6);
    if (n >= n_nodes) return;
    int j = threadIdx.x & 63;
    float x = emb[(long)h_ids[n] * 64 + j];
    float acc = b1[j];
#pragma unroll
    for (int k = 0; k < 64; ++k)
        acc = fmaf(__shfl(x, k, 64), lw1[k * 64 + j], acc);
    int b = j >> 3, o = j & 7, xbase = j & 56;
    int e1 = off[n + 1];
    for (int p = off[n]; p < e1; ++p) {
        int e = eidx[p];
        int s = src[e], r = rel[e];
        float nm = norm[e];
        float xs = emb[(long)h_ids[s] * 64 + j];
        const float* w = w1 + (long)r * 512 + b * 64 + o;
        float m = 0.f;
#pragma unroll
        for (int i = 0; i < 8; ++i)
            m = fmaf(__shfl(xs, xbase + i, 64), w[i * 8], m);
        acc = fmaf(nm, m, acc);
    }
    h1[(long)n * 64 + j] = acc;
}

// one wave per node: h2 = b2 + relu(h1[n])@lw2 + gather(relu(h1[src])) ; fused epilogue
__global__ void layer2(const float* __restrict__ h1, const int* __restrict__ src,
                       const int* __restrict__ rel, const float* __restrict__ norm,
                       const float* __restrict__ w2, const float* __restrict__ lw2,
                       const float* __restrict__ b2, const float* __restrict__ eps,
                       const int* __restrict__ off, const int* __restrict__ eidx,
                       float* __restrict__ out, int n_nodes) {
    int n = blockIdx.x * (blockDim.x >> 6) + (threadIdx.x >> 6);
    if (n >= n_nodes) return;
    int j = threadIdx.x & 63;
    float x = fmaxf(h1[(long)n * 64 + j], 0.f);
    float accA = b2[j], accB = b2[64 + j];
#pragma unroll
    for (int k = 0; k < 64; ++k) {
        float xk = __shfl(x, k, 64);
        accA = fmaf(xk, lw2[k * 128 + j], accA);
        accB = fmaf(xk, lw2[k * 128 + 64 + j], accB);
    }
    int o = j & 15, bA = j >> 4, bB = bA + 4;
    int e1 = off[n + 1];
    for (int p = off[n]; p < e1; ++p) {
        int e = eidx[p];
        int s = src[e], r = rel[e];
        float nm = norm[e];
        float xs = fmaxf(h1[(long)s * 64 + j], 0.f);
        const float* w = w2 + (long)r * 1024;
        float mA = 0.f, mB = 0.f;
#pragma unroll
        for (int i = 0; i < 8; ++i) {
            mA = fmaf(__shfl(xs, bA * 8 + i, 64), w[bA * 128 + i * 16 + o], mA);
            mB = fmaf(__shfl(xs, bB * 8 + i, 64), w[bB * 128 + i * 16 + o], mB);
        }
        accA = fmaf(nm, mA, accA);
        accB = fmaf(nm, mB, accB);
    }
    float m = accA, rv = accB;
    float sp = (rv > 20.f) ? rv : log1pf(expf(rv));
    float v = sp + 1e-8f;
    out[(long)n * 64 + j] = fmaf(sqrtf(v), eps[(long)n * 64 + j], m);
}

extern "C" void kernel_launch(void* const* d_in, const int* in_sizes, int n_in,
                              void* d_out, int out_size, void* d_ws, size_t ws_size,
                              hipStream_t stream) {
    const float* emb   = (const float*)d_in[0];
    const float* norm  = (const float*)d_in[1];
    const float* eps   = (const float*)d_in[2];
    const float* w1    = (const float*)d_in[3];
    const float* lw1   = (const float*)d_in[4];
    const float* b1    = (const float*)d_in[5];
    const float* w2    = (const float*)d_in[6];
    const float* lw2   = (const float*)d_in[7];
    const float* b2    = (const float*)d_in[8];
    const int*   h_ids = (const int*)d_in[9];
    const int*   src   = (const int*)d_in[10];
    const int*   dst   = (const int*)d_in[11];
    const int*   rel   = (const int*)d_in[12];
    float* out = (float*)d_out;

    int n_nodes = in_sizes[0] / 64;   // 50000
    int n_edges = in_sizes[10];       // 400000

    char* ws = (char*)d_ws;
    float* h1  = (float*)ws;                                   ws += (size_t)n_nodes * 64 * 4;
    int*   deg = (int*)ws;                                     ws += (size_t)n_nodes * 4;
    int*   off = (int*)ws;                                     ws += (size_t)(n_nodes + 1) * 4;
    int*   fil = (int*)ws;                                     ws += (size_t)n_nodes * 4;
    int*   eidx= (int*)ws;

    int blk = 256;
    // CSR build
    zero_deg<<<(n_nodes + blk - 1) / blk, blk, 0, stream>>>(deg, n_nodes);
    hist<<<(n_edges + blk - 1) / blk, blk, 0, stream>>>(dst, deg, n_edges);
    scan_deg<<<1, 1024, 0, stream>>>(deg, off, fil, n_nodes);
    scatter<<<(n_edges + blk - 1) / blk, blk, 0, stream>>>(dst, off, fil, eidx, n_edges);
    // fused layers (one wave per node, 4 waves/block)
    int nodes_per_blk = blk / 64;
    int grid = (n_nodes + nodes_per_blk - 1) / nodes_per_blk;
    layer1<<<grid, blk, 0, stream>>>(emb, h_ids, src, rel, norm, w1, lw1, b1, off, eidx, h1, n_nodes);
    layer2<<<grid, blk, 0, stream>>>(h1, src, rel, norm, w2, lw2, b2, eps, off, eidx, out, n_nodes);
}

// Round 3
// 442.004 us; speedup vs baseline: 1.1477x; 1.0499x over previous
//
#include <hip/hip_runtime.h>
#include <math.h>

// KGVAE: 2-layer RelGraphConv (bdd) + reparameterize, gather form, R3.
// R3: CSR-sorted packed edge meta (src|rel<<16, norm) for coalesced meta reads;
//     8-deep batched gather prefetch for MLP; memset for deg/fill.
// ws: deg[N] | fil[N] | off[N+1] | h1[N*64] f32 | pack[E] u32 | norm_s[E] f32

__global__ void hist(const int* __restrict__ dst, int* __restrict__ deg, int e) {
    int i = blockIdx.x * blockDim.x + threadIdx.x;
    if (i < e) atomicAdd(&deg[dst[i]], 1);
}

__global__ void scan_deg(const int* __restrict__ deg, int* __restrict__ off, int n) {
    __shared__ int part[1024];
    int t = threadIdx.x;
    int chunk = (n + 1023) / 1024;
    int lo = t * chunk, hi = lo + chunk;
    if (hi > n) hi = n;
    int s = 0;
    for (int i = lo; i < hi; ++i) s += deg[i];
    part[t] = s;
    __syncthreads();
    for (int d = 1; d < 1024; d <<= 1) {
        int v = (t >= d) ? part[t - d] : 0;
        __syncthreads();
        part[t] += v;
        __syncthreads();
    }
    int run = part[t] - s;
    for (int i = lo; i < hi; ++i) { off[i] = run; run += deg[i]; }
    if (t == 1023) off[n] = part[1023];
}

__global__ void scatter_pack(const int* __restrict__ src, const int* __restrict__ dst,
                             const int* __restrict__ rel, const float* __restrict__ norm,
                             const int* __restrict__ off, int* __restrict__ fil,
                             unsigned int* __restrict__ pack, float* __restrict__ norm_s,
                             int e) {
    int i = blockIdx.x * blockDim.x + threadIdx.x;
    if (i >= e) return;
    int d = dst[i];
    int p = off[d] + atomicAdd(&fil[d], 1);
    pack[p] = (unsigned)src[i] | ((unsigned)rel[i] << 16);
    norm_s[p] = norm[i];
}

// one wave per node: h1 = b1 + emb[h_ids[n]]@lw1 + sum_e nm*bdd(emb[h_ids[src]],w1[rel])
__global__ void layer1(const float* __restrict__ emb, const int* __restrict__ h_ids,
                       const float* __restrict__ w1, const float* __restrict__ lw1,
                       const float* __restrict__ b1, const int* __restrict__ off,
                       const unsigned* __restrict__ pack, const float* __restrict__ norm_s,
                       float* __restrict__ h1, int n_nodes) {
    int n = blockIdx.x * (blockDim.x >> 6) + (threadIdx.x >> 6);
    if (n >= n_nodes) return;
    int j = threadIdx.x & 63;
    float x = emb[(long)h_ids[n] * 64 + j];
    float acc = b1[j];
#pragma unroll
    for (int k = 0; k < 64; ++k)
        acc = fmaf(__shfl(x, k, 64), lw1[k * 64 + j], acc);
    int b = j >> 3, o = j & 7, xbase = j & 56;
    int e0 = off[n], e1 = off[n + 1];
    for (int win = e0; win < e1; win += 64) {
        int wcnt = e1 - win; if (wcnt > 64) wcnt = 64;
        // coalesced meta for up to 64 edges in parallel
        unsigned u = (j < wcnt) ? pack[win + j] : 0u;
        float nm_ = (j < wcnt) ? norm_s[win + j] : 0.f;
        int hs_ = (j < wcnt) ? h_ids[u & 0xFFFFu] : 0;
        int r_ = (int)(u >> 16);
        for (int base = 0; base < wcnt; base += 8) {
            int cnt = wcnt - base; if (cnt > 8) cnt = 8;
            float xs[8];
#pragma unroll
            for (int c = 0; c < 8; ++c)
                if (c < cnt) xs[c] = emb[(long)__shfl(hs_, base + c, 64) * 64 + j];
#pragma unroll
            for (int c = 0; c < 8; ++c)
                if (c < cnt) {
                    int r = __shfl(r_, base + c, 64);
                    float nm = __shfl(nm_, base + c, 64);
                    const float* w = w1 + (long)r * 512 + b * 64 + o;
                    float m = 0.f;
#pragma unroll
                    for (int i = 0; i < 8; ++i)
                        m = fmaf(__shfl(xs[c], xbase + i, 64), w[i * 8], m);
                    acc = fmaf(nm, m, acc);
                }
        }
    }
    h1[(long)n * 64 + j] = acc;
}

// one wave per node: h2 = b2 + relu(h1[n])@lw2 + gather msgs; fused reparam epilogue
__global__ void layer2(const float* __restrict__ h1, const float* __restrict__ w2,
                       const float* __restrict__ lw2, const float* __restrict__ b2,
                       const float* __restrict__ eps, const int* __restrict__ off,
                       const unsigned* __restrict__ pack, const float* __restrict__ norm_s,
                       float* __restrict__ out, int n_nodes) {
    int n = blockIdx.x * (blockDim.x >> 6) + (threadIdx.x >> 6);
    if (n >= n_nodes) return;
    int j = threadIdx.x & 63;
    float x = fmaxf(h1[(long)n * 64 + j], 0.f);
    float accA = b2[j], accB = b2[64 + j];
#pragma unroll
    for (int k = 0; k < 64; ++k) {
        float xk = __shfl(x, k, 64);
        accA = fmaf(xk, lw2[k * 128 + j], accA);
        accB = fmaf(xk, lw2[k * 128 + 64 + j], accB);
    }
    int o = j & 15, bA = j >> 4, bB = bA + 4;
    int e0 = off[n], e1 = off[n + 1];
    for (int win = e0; win < e1; win += 64) {
        int wcnt = e1 - win; if (wcnt > 64) wcnt = 64;
        unsigned u = (j < wcnt) ? pack[win + j] : 0u;
        float nm_ = (j < wcnt) ? norm_s[win + j] : 0.f;
        int s_ = (int)(u & 0xFFFFu);
        int r_ = (int)(u >> 16);
        for (int base = 0; base < wcnt; base += 8) {
            int cnt = wcnt - base; if (cnt > 8) cnt = 8;
            float xs[8];
#pragma unroll
            for (int c = 0; c < 8; ++c)
                if (c < cnt) xs[c] = fmaxf(h1[(long)__shfl(s_, base + c, 64) * 64 + j], 0.f);
#pragma unroll
            for (int c = 0; c < 8; ++c)
                if (c < cnt) {
                    int r = __shfl(r_, base + c, 64);
                    float nm = __shfl(nm_, base + c, 64);
                    const float* w = w2 + (long)r * 1024;
                    float mA = 0.f, mB = 0.f;
#pragma unroll
                    for (int i = 0; i < 8; ++i) {
                        mA = fmaf(__shfl(xs[c], bA * 8 + i, 64), w[bA * 128 + i * 16 + o], mA);
                        mB = fmaf(__shfl(xs[c], bB * 8 + i, 64), w[bB * 128 + i * 16 + o], mB);
                    }
                    accA = fmaf(nm, mA, accA);
                    accB = fmaf(nm, mB, accB);
                }
        }
    }
    float m = accA, rv = accB;
    float sp = (rv > 20.f) ? rv : log1pf(expf(rv));
    float v = sp + 1e-8f;
    out[(long)n * 64 + j] = fmaf(sqrtf(v), eps[(long)n * 64 + j], m);
}

extern "C" void kernel_launch(void* const* d_in, const int* in_sizes, int n_in,
                              void* d_out, int out_size, void* d_ws, size_t ws_size,
                              hipStream_t stream) {
    const float* emb   = (const float*)d_in[0];
    const float* norm  = (const float*)d_in[1];
    const float* eps   = (const float*)d_in[2];
    const float* w1    = (const float*)d_in[3];
    const float* lw1   = (const float*)d_in[4];
    const float* b1    = (const float*)d_in[5];
    const float* w2    = (const float*)d_in[6];
    const float* lw2   = (const float*)d_in[7];
    const float* b2    = (const float*)d_in[8];
    const int*   h_ids = (const int*)d_in[9];
    const int*   src   = (const int*)d_in[10];
    const int*   dst   = (const int*)d_in[11];
    const int*   rel   = (const int*)d_in[12];
    float* out = (float*)d_out;

    int n_nodes = in_sizes[0] / 64;   // 50000
    int n_edges = in_sizes[10];       // 400000

    char* ws = (char*)d_ws;
    int*   deg    = (int*)ws;                         ws += (size_t)n_nodes * 4;
    int*   fil    = (int*)ws;                         ws += (size_t)n_nodes * 4;
    int*   off    = (int*)ws;                         ws += (size_t)(n_nodes + 1) * 4;
    float* h1     = (float*)ws;                       ws += (size_t)n_nodes * 64 * 4;
    unsigned* pk  = (unsigned*)ws;                    ws += (size_t)n_edges * 4;
    float* norm_s = (float*)ws;

    int blk = 256;
    // CSR build (deg & fil zeroed in one contiguous memset)
    hipMemsetAsync(deg, 0, (size_t)n_nodes * 8, stream);
    hist<<<(n_edges + blk - 1) / blk, blk, 0, stream>>>(dst, deg, n_edges);
    scan_deg<<<1, 1024, 0, stream>>>(deg, off, n_nodes);
    scatter_pack<<<(n_edges + blk - 1) / blk, blk, 0, stream>>>(src, dst, rel, norm, off, fil, pk, norm_s, n_edges);
    // fused layers (one wave per node, 4 waves/block)
    int grid = (n_nodes + 3) / 4;
    layer1<<<grid, blk, 0, stream>>>(emb, h_ids, w1, lw1, b1, off, pk, norm_s, h1, n_nodes);
    layer2<<<grid, blk, 0, stream>>>(h1, w2, lw2, b2, eps, off, pk, norm_s, out, n_nodes);
}